// Round 6
// baseline (3215.536 us; speedup 1.0000x reference)
//
#include <hip/hip_runtime.h>
#include <stdint.h>
#include <math.h>

typedef __attribute__((ext_vector_type(8))) short short8;
typedef __attribute__((ext_vector_type(4))) float floatx4;

#define B_DIM 2048
#define O_DIM 512
#define H_DIM 1024
#define P_DIM 1024
#define C_DIM 512
#define K_BIG 2560   // H + P + C (WbT row length, unchanged)
#define K_REC 1536   // P + C    (recurrent X width)
#define TAU 0.25f
#define OMT 0.75f
#define NBLK 768     // persistent grid: 3 blocks/CU x 256 CUs

// s_waitcnt imm (gfx9): vmcnt [3:0]+[15:14], exp [6:4]=7, lgkm [11:8]=15 (no wait)
#define VMCNT(n) (((n) & 15) | (((n) >> 4) << 14) | 0x0F70)
#define MEMFENCE asm volatile("" ::: "memory")

__device__ inline short f2bf(float f) {
  uint32_t u = __float_as_uint(f);
  u += 0x7FFFu + ((u >> 16) & 1u);   // round-to-nearest-even
  return (short)(u >> 16);
}

__device__ inline float sigmoidf_(float x) {
  return 1.0f / (1.0f + __expf(-x));
}

__device__ inline void async_copy16(const void* g, void* l) {
  __builtin_amdgcn_global_load_lds((__attribute__((address_space(1))) void*)g,
                                   (__attribute__((address_space(3))) void*)l,
                                   16, 0, 0);
}

// [R6] manual grid barrier (regular launch, graph-capturable).
// Safe because grid==residency capacity (LDS 3x48KB<=160KB, VGPR capped by
// __launch_bounds__(256,3)) -> all 768 blocks co-resident, no deadlock.
// One counter per sync point (no reset). Device-scope atomics + fences give
// cross-XCD visibility (per-XCD L2s are not coherent).
__device__ inline void gridbar(uint32_t* ctr) {
  __syncthreads();
  __threadfence();                                       // release prior stores
  if (threadIdx.x == 0) {
    __hip_atomic_fetch_add(ctr, 1u, __ATOMIC_ACQ_REL, __HIP_MEMORY_SCOPE_AGENT);
    while (__hip_atomic_load(ctr, __ATOMIC_ACQUIRE, __HIP_MEMORY_SCOPE_AGENT) < NBLK)
      __builtin_amdgcn_s_sleep(2);
  }
  __syncthreads();
  __threadfence();                                       // acquire: drop stale lines
}

// ---------------------------------------------------------------------------
// 64x64 block tile, BK=64, ring-3 LDS (3 x 16KB), prefetch distance 2,
// ONE barrier per K-iter. 4 waves in 2x2, wave = 32x32 via 2x2 frags.
// (The proven core — used inside the persistent step kernel.)
// ---------------------------------------------------------------------------
__device__ inline void gemm_core64(const short* __restrict__ A, int lda,
                                   const short* __restrict__ BT, int ldb,
                                   int Ktot, short* lds, floatx4 acc[2][2]) {
  const int tid = threadIdx.x, lane = tid & 63, w = tid >> 6;
  const int wm = w >> 1, wn = w & 1;
  const int fm = lane & 15, hi = lane >> 4;

  const int r0 = tid >> 3;                       // row 0..31
  const int g0 = (tid & 7) ^ (r0 & 7);           // swizzled global chunk
  const short* gA0 = A + (size_t)r0 * lda + g0 * 8;
  const short* gA1 = A + (size_t)(r0 + 32) * lda + g0 * 8;   // (r0+32)&7 == r0&7
  const short* gB0 = BT + (size_t)r0 * ldb + g0 * 8;
  const short* gB1 = BT + (size_t)(r0 + 32) * ldb + g0 * 8;
  const int dA0 = tid * 8, dA1 = (256 + tid) * 8;
  const int dB0 = 4096 + tid * 8, dB1 = 4096 + (256 + tid) * 8;

  const int nIter = Ktot >> 6;

  auto stage = [&](int t) {
    short* d = lds + (t % 3) * 8192;
    int ko = t * 64;
    async_copy16(gA0 + ko, d + dA0);
    async_copy16(gA1 + ko, d + dA1);
    async_copy16(gB0 + ko, d + dB0);
    async_copy16(gB1 + ko, d + dB1);
  };

  const int sw = fm & 7;

  stage(0);
  stage(1);
  for (int it = 0; it < nIter; ++it) {
    if (it + 1 < nIter) __builtin_amdgcn_s_waitcnt(VMCNT(4));
    else                __builtin_amdgcn_s_waitcnt(VMCNT(0));
    MEMFENCE;
    __builtin_amdgcn_s_barrier();
    MEMFENCE;
    if (it + 2 < nIter) stage(it + 2);
    const short* sb = lds + (it % 3) * 8192;
#pragma unroll
    for (int sl = 0; sl < 2; ++sl) {
      short8 a[2], b[2];
#pragma unroll
      for (int i = 0; i < 2; ++i) {
        int ar = wm * 32 + i * 16 + fm;
        a[i] = *(const short8*)&sb[(ar * 8 + ((sl * 4 + hi) ^ sw)) * 8];
      }
#pragma unroll
      for (int j = 0; j < 2; ++j) {
        int br = wn * 32 + j * 16 + fm;
        b[j] = *(const short8*)&sb[4096 + (br * 8 + ((sl * 4 + hi) ^ sw)) * 8];
      }
#pragma unroll
      for (int i = 0; i < 2; ++i)
#pragma unroll
        for (int j = 0; j < 2; ++j)
          acc[i][j] = __builtin_amdgcn_mfma_f32_16x16x32_bf16(a[i], b[j], acc[i][j], 0, 0, 0);
    }
  }
  MEMFENCE;
}

// ---------------------------------------------------------------------------
// 128x64 block tile, BK=64, ring-3 (3 x 24KB). Kept for k_gemm_oh (working).
// ---------------------------------------------------------------------------
__device__ inline void gemm_core128(const short* __restrict__ A, int lda,
                                    const short* __restrict__ BT, int ldb,
                                    int Ktot, short* lds, floatx4 acc[4][2]) {
  const int tid = threadIdx.x, lane = tid & 63, w = tid >> 6;
  const int wm = w >> 1, wn = w & 1;
  const int fm = lane & 15, hi = lane >> 4;

  const int r0 = tid >> 3;
  const int g0 = (tid & 7) ^ (r0 & 7);
  const short* gA0 = A + (size_t)r0 * lda + g0 * 8;
  const short* gA1 = A + (size_t)(r0 + 32) * lda + g0 * 8;
  const short* gA2 = A + (size_t)(r0 + 64) * lda + g0 * 8;
  const short* gA3 = A + (size_t)(r0 + 96) * lda + g0 * 8;
  const short* gB0 = BT + (size_t)r0 * ldb + g0 * 8;
  const short* gB1 = BT + (size_t)(r0 + 32) * ldb + g0 * 8;
  const int dA0 = tid * 8,          dA1 = (256 + tid) * 8;
  const int dA2 = (512 + tid) * 8,  dA3 = (768 + tid) * 8;
  const int dB0 = 8192 + tid * 8,   dB1 = 8192 + (256 + tid) * 8;

  const int nIter = Ktot >> 6;

  auto stage = [&](int t) {
    short* d = lds + (t % 3) * 12288;
    int ko = t * 64;
    async_copy16(gA0 + ko, d + dA0);
    async_copy16(gA1 + ko, d + dA1);
    async_copy16(gA2 + ko, d + dA2);
    async_copy16(gA3 + ko, d + dA3);
    async_copy16(gB0 + ko, d + dB0);
    async_copy16(gB1 + ko, d + dB1);
  };

  const int sw = fm & 7;

  stage(0);
  stage(1);
  for (int it = 0; it < nIter; ++it) {
    if (it + 1 < nIter) __builtin_amdgcn_s_waitcnt(VMCNT(6));
    else                __builtin_amdgcn_s_waitcnt(VMCNT(0));
    MEMFENCE;
    __builtin_amdgcn_s_barrier();
    MEMFENCE;
    if (it + 2 < nIter) stage(it + 2);
    const short* sb = lds + (it % 3) * 12288;
#pragma unroll
    for (int sl = 0; sl < 2; ++sl) {
      short8 a[4], b[2];
#pragma unroll
      for (int i = 0; i < 4; ++i) {
        int ar = wm * 64 + i * 16 + fm;
        a[i] = *(const short8*)&sb[(ar * 8 + ((sl * 4 + hi) ^ sw)) * 8];
      }
#pragma unroll
      for (int j = 0; j < 2; ++j) {
        int br = wn * 32 + j * 16 + fm;
        b[j] = *(const short8*)&sb[8192 + (br * 8 + ((sl * 4 + hi) ^ sw)) * 8];
      }
#pragma unroll
      for (int i = 0; i < 4; ++i)
#pragma unroll
        for (int j = 0; j < 2; ++j)
          acc[i][j] = __builtin_amdgcn_mfma_f32_16x16x32_bf16(a[i], b[j], acc[i][j], 0, 0, 0);
    }
  }
  MEMFENCE;
}

// ---------------------------------------------------------------------------
// 256x128 block tile, BK=32, ring-3 (3 x 24KB = 72KB -> 2 blocks/CU),
// 512 threads = 8 waves in 4m x 2n, wave-tile 64x64. Swizzle (row>>1)&3
// (verified conflict-free in R3). Used for the hoisted GEMM (k_pah).
// ---------------------------------------------------------------------------
__device__ inline void gemm_core256x128(const short* __restrict__ A, int lda,
                                        const short* __restrict__ BT, int ldb,
                                        int Ktot, short* lds, floatx4 acc[4][4]) {
  const int tid = threadIdx.x, lane = tid & 63, w = tid >> 6;
  const int wm = w >> 1, wn = w & 1;          // 4 x 2 wave grid
  const int fm = lane & 15, hi = lane >> 4;

  const int r0 = tid >> 2;                    // row 0..127
  const int c0 = tid & 3;
  const int g0 = c0 ^ ((r0 >> 1) & 3);        // (r0+128)>>1 & 3 == (r0>>1)&3
  const short* gA0 = A + (size_t)r0 * lda + g0 * 8;
  const short* gA1 = A + (size_t)(r0 + 128) * lda + g0 * 8;
  const short* gB0 = BT + (size_t)r0 * ldb + g0 * 8;
  const int dA0 = tid * 8, dA1 = (512 + tid) * 8;
  const int dB0 = 8192 + tid * 8;             // B base = 8192 shorts (16KB)

  const int nIter = Ktot >> 5;

  auto stage = [&](int t) {
    short* d = lds + (t % 3) * 12288;         // slot = 24KB = 12288 shorts
    int ko = t * 32;
    async_copy16(gA0 + ko, d + dA0);
    async_copy16(gA1 + ko, d + dA1);
    async_copy16(gB0 + ko, d + dB0);
  };

  const int swz = (fm >> 1) & 3;              // (row>>1)&3 for row = 16k + fm

  stage(0);
  stage(1);
  for (int it = 0; it < nIter; ++it) {
    if (it + 1 < nIter) __builtin_amdgcn_s_waitcnt(VMCNT(3));
    else                __builtin_amdgcn_s_waitcnt(VMCNT(0));
    MEMFENCE;
    __builtin_amdgcn_s_barrier();
    MEMFENCE;
    if (it + 2 < nIter) stage(it + 2);
    const short* sb = lds + (it % 3) * 12288;
    short8 a[4], b[4];
#pragma unroll
    for (int i = 0; i < 4; ++i) {
      int ar = wm * 64 + i * 16 + fm;         // 0..255
      a[i] = *(const short8*)&sb[(ar * 4 + (hi ^ swz)) * 8];
    }
#pragma unroll
    for (int j = 0; j < 4; ++j) {
      int br = wn * 64 + j * 16 + fm;         // 0..127
      b[j] = *(const short8*)&sb[8192 + (br * 4 + (hi ^ swz)) * 8];
    }
#pragma unroll
    for (int i = 0; i < 4; ++i)
#pragma unroll
      for (int j = 0; j < 4; ++j)
        acc[i][j] = __builtin_amdgcn_mfma_f32_16x16x32_bf16(a[i], b[j], acc[i][j], 0, 0, 0);
  }
  MEMFENCE;
}

// ---------------- setup kernels ----------------

// [R6] all weight/input preps fused into one dispatch; also zeroes barrier.
// blocks [0,10240): WbT  [1024 n][2560 k] = [w_hp ; w_pp(0 diag) ; w_cp]^T
// blocks [10240,12288): WpcT [512 n][1024 k]
// blocks [12288,14336): WohT [1024 n][512 k]
// blocks [14336,18432): inb (bf16 cast of inputs)
__global__ void k_build_all(const float* __restrict__ w_hp, const float* __restrict__ w_pp,
                            const float* __restrict__ w_cp, const float* __restrict__ w_pc,
                            const float* __restrict__ w_oh, const float* __restrict__ inp,
                            short* __restrict__ WbT, short* __restrict__ WpcT,
                            short* __restrict__ WohT, short* __restrict__ inb,
                            uint32_t* __restrict__ bar) {
  int bx = blockIdx.x, tid = threadIdx.x;
  if (bx == 0 && tid < 16) bar[tid] = 0;
  if (bx < 10240) {
    int idx = bx * 256 + tid;                     // 1024*2560
    int n = idx / K_BIG, k = idx - n * K_BIG;
    float v;
    if (k < 1024) v = w_hp[k * P_DIM + n];
    else if (k < 2048) { int r = k - 1024; v = (r == n) ? 0.f : w_pp[r * P_DIM + n]; }
    else v = w_cp[(k - 2048) * P_DIM + n];
    WbT[idx] = f2bf(v);
  } else if (bx < 12288) {
    int idx = (bx - 10240) * 256 + tid;           // 512*1024
    int n = idx >> 10, k = idx & 1023;
    WpcT[idx] = f2bf(w_pc[k * C_DIM + n]);
  } else if (bx < 14336) {
    int idx = (bx - 12288) * 256 + tid;           // 1024*512
    int n = idx >> 9, k = idx & 511;
    WohT[idx] = f2bf(w_oh[k * H_DIM + n]);
  } else {
    int idx = (bx - 14336) * 256 + tid;           // 2048*512
    inb[idx] = f2bf(inp[idx]);
  }
}

// oh = inputs @ w_oh + bias_h   (M=2048,N=1024,K=512) grid 16x16=256, 128x64 tiles
__global__ __launch_bounds__(256, 2) void k_gemm_oh(const short* __restrict__ inb,
                                                    const short* __restrict__ WohT,
                                                    const float* __restrict__ bias_h,
                                                    float* __restrict__ oh) {
  __shared__ short lds[36864];
  floatx4 acc[4][2] = {};
  int m0 = (blockIdx.x & 15) * 128, n0 = (blockIdx.x >> 4) * 64;
  gemm_core128(inb + (size_t)m0 * O_DIM, O_DIM, WohT + (size_t)n0 * O_DIM, O_DIM,
               O_DIM, lds, acc);
  const int lane = threadIdx.x & 63;
  const int fm = lane & 15, hi = lane >> 4;
  const int w = threadIdx.x >> 6, wm = w >> 1, wn = w & 1;
#pragma unroll
  for (int i = 0; i < 4; ++i)
#pragma unroll
    for (int j = 0; j < 2; ++j)
#pragma unroll
      for (int r = 0; r < 4; ++r) {
        int m = m0 + wm * 64 + i * 16 + hi * 4 + r;
        int n = n0 + wn * 32 + j * 16 + fm;
        oh[(size_t)m * H_DIM + n] = acc[i][j][r] + bias_h[n];
      }
}

// Ah[t'][m][n] = bf16(sigmoid((1 - 0.75^t') * oh[m][n])), t' = 1..11
__global__ void k_ah(const float* __restrict__ oh, short* __restrict__ Ah) {
  int tp = blockIdx.y + 1;                        // t' = 1..11
  float o = 1.0f;
  for (int i = 0; i < 11; ++i) if (i < tp) o *= OMT;   // exact 0.75^t'
  float ct = 1.0f - o;
  size_t idx = ((size_t)blockIdx.x * 256 + threadIdx.x) * 8;   // over 2048*1024
  const float4* s = (const float4*)(oh + idx);
  float4 v0 = s[0], v1 = s[1];
  short8 r;
  r[0] = f2bf(sigmoidf_(ct * v0.x)); r[1] = f2bf(sigmoidf_(ct * v0.y));
  r[2] = f2bf(sigmoidf_(ct * v0.z)); r[3] = f2bf(sigmoidf_(ct * v0.w));
  r[4] = f2bf(sigmoidf_(ct * v1.x)); r[5] = f2bf(sigmoidf_(ct * v1.y));
  r[6] = f2bf(sigmoidf_(ct * v1.z)); r[7] = f2bf(sigmoidf_(ct * v1.w));
  *(short8*)(Ah + (size_t)blockIdx.y * B_DIM * H_DIM + idx) = r;
}

// P_ah = Ah[11*2048 x 1024] @ w_hp  (K=1024), raw f32 -> Pdst (= out + 2048*1024)
// grid 704 = 88 m-panels (256 rows) x 8 n-panels (128 cols), 512 threads.
// XCD-chunked bijective remap (704 = 8*88).
__global__ __launch_bounds__(512, 4) void k_pah(const short* __restrict__ Ah,
                                                const short* __restrict__ WbT,
                                                float* __restrict__ Pdst) {
  __shared__ short lds[36864];            // 72KB: 3-ring x (16KB A + 8KB B)
  floatx4 acc[4][4] = {};
  int logical = (blockIdx.x & 7) * 88 + (blockIdx.x >> 3);
  int m = logical >> 3, n = logical & 7;
  int m0 = m * 256, n0 = n * 128;
  gemm_core256x128(Ah + (size_t)m0 * H_DIM, H_DIM, WbT + (size_t)n0 * K_BIG, K_BIG,
                   H_DIM, lds, acc);
  const int lane = threadIdx.x & 63;
  const int fm = lane & 15, hi = lane >> 4;
  const int w = threadIdx.x >> 6, wm = w >> 1, wn = w & 1;
#pragma unroll
  for (int i = 0; i < 4; ++i)
#pragma unroll
    for (int j = 0; j < 4; ++j)
#pragma unroll
      for (int r = 0; r < 4; ++r) {
        int rr = m0 + wm * 64 + i * 16 + hi * 4 + r;
        int nn = n0 + wn * 64 + j * 16 + fm;
        Pdst[(size_t)rr * P_DIM + nn] = acc[i][j][r];
      }
}

// Step 1 is rank-1 (all states = 0.5): column sums of WbT / WpcT.
// 384 blocks x 4 waves; wave r sums one row.
__global__ void k_step1a(const short* __restrict__ WbT, const short* __restrict__ WpcT,
                         const float* __restrict__ bias_p, const float* __restrict__ bias_c,
                         float* __restrict__ p1v, float* __restrict__ ap1v,
                         float* __restrict__ c1v, float* __restrict__ ac1v) {
  int r = blockIdx.x * 4 + (threadIdx.x >> 6);
  int lane = threadIdx.x & 63;
  float s = 0.f;
  if (r < 1024) {
    const short* row = WbT + (size_t)r * K_BIG;
    for (int k = lane; k < K_BIG; k += 64)
      s += __uint_as_float(((uint32_t)(uint16_t)row[k]) << 16);
  } else {
    const short* row = WpcT + (size_t)(r - 1024) * P_DIM;
    for (int k = lane; k < P_DIM; k += 64)
      s += __uint_as_float(((uint32_t)(uint16_t)row[k]) << 16);
  }
#pragma unroll
  for (int off = 32; off > 0; off >>= 1) s += __shfl_down(s, off, 64);
  if (lane == 0) {
    if (r < 1024) {
      float pv = TAU * (0.5f * s + bias_p[r]);
      p1v[r] = pv; ap1v[r] = sigmoidf_(pv);
    } else {
      int n = r - 1024;
      float cv = TAU * (0.5f * s + bias_c[n]);
      c1v[n] = cv; ac1v[n] = sigmoidf_(cv);
    }
  }
}

// ---------------- [R6] persistent recurrent chain (regular launch) ----------
// phase-0 broadcast of the step-1 closed form, then steps t=2..12 separated
// by the manual gridbar. 768 blocks x 256 threads = exactly 3 blocks/CU;
// each CU holds 2 big + 1 small block (balanced -> minimal barrier stall).
__global__ __launch_bounds__(256, 3) void k_steps(short* __restrict__ XA,
                                                  short* __restrict__ XB,
                                                  const short* __restrict__ WbT,
                                                  const short* __restrict__ WpcT,
                                                  const float* __restrict__ bias_p,
                                                  const float* __restrict__ bias_c,
                                                  float* __restrict__ p,
                                                  float* __restrict__ c,
                                                  float* __restrict__ out,
                                                  const float* __restrict__ p1v,
                                                  const float* __restrict__ ap1v,
                                                  const float* __restrict__ c1v,
                                                  const float* __restrict__ ac1v,
                                                  uint32_t* __restrict__ bar) {
  __shared__ short lds[24576];
  const int tid = threadIdx.x;
  const int bx = blockIdx.x;

  // phase 0: step-1 fill (X1 = XA, out[0], p, c) from the rank-1 closed form
  for (size_t idx = (size_t)bx * 256 + tid; idx < (size_t)B_DIM * K_REC;
       idx += (size_t)NBLK * 256) {
    int m = (int)(idx / K_REC);
    int n = (int)(idx - (size_t)m * K_REC);
    if (n < P_DIM) {
      float ap = ap1v[n];
      XA[idx] = f2bf(ap);
      out[(size_t)m * P_DIM + n] = ap;
      p[(size_t)m * P_DIM + n] = p1v[n];
    } else {
      int nn = n - P_DIM;
      XA[idx] = f2bf(ac1v[nn]);
      c[(size_t)m * C_DIM + nn] = c1v[nn];
    }
  }

  const int lane = tid & 63;
  const int fm = lane & 15, hi = lane >> 4;
  const int w = tid >> 6, wm = w >> 1, wn = w & 1;

  for (int t = 2; t <= 12; ++t) {
    gridbar(&bar[t - 2]);
    const short* Xc = ((t - 1) & 1) ? XA : XB;
    short* Xn = (t & 1) ? XA : XB;
    float* out_t = out + (size_t)(t - 1) * B_DIM * P_DIM;
    floatx4 acc[2][2] = {};

    if (bx < 512) {
      // big GEMM: X(2048x1536) @ WbT[:,1024:]^T (24 iters) -> p/ap update
      int m0 = (bx & 31) * 64, n0 = (bx >> 5) * 64;
      gemm_core64(Xc + (size_t)m0 * K_REC, K_REC,
                  WbT + (size_t)n0 * K_BIG + H_DIM, K_BIG,
                  K_REC, lds, acc);
#pragma unroll
      for (int i = 0; i < 2; ++i)
#pragma unroll
        for (int j = 0; j < 2; ++j)
#pragma unroll
          for (int r = 0; r < 4; ++r) {
            int m = m0 + wm * 32 + i * 16 + hi * 4 + r;
            int n = n0 + wn * 32 + j * 16 + fm;
            size_t o = (size_t)m * P_DIM + n;
            float pn = TAU * (acc[i][j][r] + out_t[o] + bias_p[n]) + OMT * p[o];
            p[o] = pn;
            float ap = sigmoidf_(pn);
            out_t[o] = ap;
            Xn[(size_t)m * K_REC + n] = f2bf(ap);
          }
    } else {
      // small GEMM: ap(2048x1024) @ WpcT^T (16 iters) -> c/ac update
      int v = bx - 512;
      int m0 = (v >> 3) * 64, n0 = (v & 7) * 64;
      gemm_core64(Xc + (size_t)m0 * K_REC, K_REC,
                  WpcT + (size_t)n0 * P_DIM, P_DIM,
                  P_DIM, lds, acc);
#pragma unroll
      for (int i = 0; i < 2; ++i)
#pragma unroll
        for (int j = 0; j < 2; ++j)
#pragma unroll
          for (int r = 0; r < 4; ++r) {
            int m = m0 + wm * 32 + i * 16 + hi * 4 + r;
            int n = n0 + wn * 32 + j * 16 + fm;
            size_t o = (size_t)m * C_DIM + n;
            float cn = TAU * (acc[i][j][r] + bias_c[n]) + OMT * c[o];
            c[o] = cn;
            Xn[(size_t)m * K_REC + H_DIM + n] = f2bf(sigmoidf_(cn));
          }
    }
  }
}

extern "C" void kernel_launch(void* const* d_in, const int* in_sizes, int n_in,
                              void* d_out, int out_size, void* d_ws, size_t ws_size,
                              hipStream_t stream) {
  const float* inputs = (const float*)d_in[0];
  const float* w_oh   = (const float*)d_in[1];
  const float* w_hp   = (const float*)d_in[2];
  const float* w_pp   = (const float*)d_in[3];
  const float* w_pc   = (const float*)d_in[4];
  const float* w_cp   = (const float*)d_in[5];
  const float* bias_h = (const float*)d_in[6];
  const float* bias_p = (const float*)d_in[7];
  const float* bias_c = (const float*)d_in[8];
  float* out = (float*)d_out;

  char* ws = (char*)d_ws;
  auto alloc = [&](size_t bytes) {
    char* q = ws;
    ws += (bytes + 255) & ~(size_t)255;
    return q;
  };
  short* WbT  = (short*)alloc((size_t)P_DIM * K_BIG * 2);          // 5.2 MB
  short* WpcT = (short*)alloc((size_t)C_DIM * P_DIM * 2);          // 1 MB
  short* WohT = (short*)alloc((size_t)H_DIM * O_DIM * 2);          // 1 MB
  short* inb  = (short*)alloc((size_t)B_DIM * O_DIM * 2);          // 2 MB
  float* oh   = (float*)alloc((size_t)B_DIM * H_DIM * 4);          // 8 MB
  short* Ah   = (short*)alloc((size_t)11 * B_DIM * H_DIM * 2);     // 46 MB
  short* XA   = (short*)alloc((size_t)B_DIM * K_REC * 2);          // 6.3 MB
  short* XB   = (short*)alloc((size_t)B_DIM * K_REC * 2);          // 6.3 MB
  float* p    = (float*)alloc((size_t)B_DIM * P_DIM * 4);          // 8 MB
  float* c    = (float*)alloc((size_t)B_DIM * C_DIM * 4);          // 4 MB
  float* p1v  = (float*)alloc(1024 * 4);
  float* ap1v = (float*)alloc(1024 * 4);
  float* c1v  = (float*)alloc(512 * 4);
  float* ac1v = (float*)alloc(512 * 4);
  uint32_t* bar = (uint32_t*)alloc(64);

  // fused weight/input prep (also zeroes bar counters)
  k_build_all<<<dim3(18432), 256, 0, stream>>>(w_hp, w_pp, w_cp, w_pc, w_oh, inputs,
                                               WbT, WpcT, WohT, inb, bar);

  // oh = inputs @ w_oh + bias_h; Ah[t'] = sigmoid((1-0.75^t') oh), t'=1..11
  k_gemm_oh<<<dim3(256), 256, 0, stream>>>(inb, WohT, bias_h, oh);
  k_ah<<<dim3((B_DIM * H_DIM) / (256 * 8), 11), 256, 0, stream>>>(oh, Ah);

  // hoisted ah-part of the p pre-activation, stored into out slots 1..11
  k_pah<<<dim3(704), 512, 0, stream>>>(Ah, WbT, out + (size_t)B_DIM * P_DIM);

  // step 1 closed form (all states 0.5 -> rank-1)
  k_step1a<<<dim3(384), 256, 0, stream>>>(WbT, WpcT, bias_p, bias_c, p1v, ap1v, c1v, ac1v);

  // persistent chain: phase-0 fill + steps t=2..12 (regular launch, manual bar)
  k_steps<<<dim3(NBLK), 256, 0, stream>>>(XA, XB, WbT, WpcT, bias_p, bias_c,
                                          p, c, out, p1v, ap1v, c1v, ac1v, bar);
}

// Round 7
// 463.062 us; speedup vs baseline: 6.9441x; 6.9441x over previous
//
#include <hip/hip_runtime.h>
#include <stdint.h>
#include <math.h>

typedef __attribute__((ext_vector_type(8))) short short8;
typedef __attribute__((ext_vector_type(4))) float floatx4;

#define B_DIM 2048
#define O_DIM 512
#define H_DIM 1024
#define P_DIM 1024
#define C_DIM 512
#define K_BIG 2560   // H + P + C (WbT row length)
#define K_REC 1536   // P + C    (recurrent X width)
#define TAU 0.25f
#define OMT 0.75f

// s_waitcnt imm (gfx9): vmcnt [3:0]+[15:14], exp [6:4]=7, lgkm [11:8]=15 (no wait)
#define VMCNT(n) (((n) & 15) | (((n) >> 4) << 14) | 0x0F70)
#define MEMFENCE asm volatile("" ::: "memory")

__device__ inline short f2bf(float f) {
  uint32_t u = __float_as_uint(f);
  u += 0x7FFFu + ((u >> 16) & 1u);   // round-to-nearest-even
  return (short)(u >> 16);
}

__device__ inline float sigmoidf_(float x) {
  return 1.0f / (1.0f + __expf(-x));
}

__device__ inline void async_copy16(const void* g, void* l) {
  __builtin_amdgcn_global_load_lds((__attribute__((address_space(1))) void*)g,
                                   (__attribute__((address_space(3))) void*)l,
                                   16, 0, 0);
}

// ---------------------------------------------------------------------------
// 64x64 block tile, BK=64, ring-3 LDS (3 x 16KB), prefetch distance 2,
// ONE barrier per K-iter. 4 waves in 2x2, wave = 32x32 via 2x2 frags.
// (The proven core — used in the per-step kernel.)
// ---------------------------------------------------------------------------
__device__ inline void gemm_core64(const short* __restrict__ A, int lda,
                                   const short* __restrict__ BT, int ldb,
                                   int Ktot, short* lds, floatx4 acc[2][2]) {
  const int tid = threadIdx.x, lane = tid & 63, w = tid >> 6;
  const int wm = w >> 1, wn = w & 1;
  const int fm = lane & 15, hi = lane >> 4;

  const int r0 = tid >> 3;                       // row 0..31
  const int g0 = (tid & 7) ^ (r0 & 7);           // swizzled global chunk
  const short* gA0 = A + (size_t)r0 * lda + g0 * 8;
  const short* gA1 = A + (size_t)(r0 + 32) * lda + g0 * 8;   // (r0+32)&7 == r0&7
  const short* gB0 = BT + (size_t)r0 * ldb + g0 * 8;
  const short* gB1 = BT + (size_t)(r0 + 32) * ldb + g0 * 8;
  const int dA0 = tid * 8, dA1 = (256 + tid) * 8;
  const int dB0 = 4096 + tid * 8, dB1 = 4096 + (256 + tid) * 8;

  const int nIter = Ktot >> 6;

  auto stage = [&](int t) {
    short* d = lds + (t % 3) * 8192;
    int ko = t * 64;
    async_copy16(gA0 + ko, d + dA0);
    async_copy16(gA1 + ko, d + dA1);
    async_copy16(gB0 + ko, d + dB0);
    async_copy16(gB1 + ko, d + dB1);
  };

  const int sw = fm & 7;

  stage(0);
  stage(1);
  for (int it = 0; it < nIter; ++it) {
    if (it + 1 < nIter) __builtin_amdgcn_s_waitcnt(VMCNT(4));
    else                __builtin_amdgcn_s_waitcnt(VMCNT(0));
    MEMFENCE;
    __builtin_amdgcn_s_barrier();
    MEMFENCE;
    if (it + 2 < nIter) stage(it + 2);
    const short* sb = lds + (it % 3) * 8192;
#pragma unroll
    for (int sl = 0; sl < 2; ++sl) {
      short8 a[2], b[2];
#pragma unroll
      for (int i = 0; i < 2; ++i) {
        int ar = wm * 32 + i * 16 + fm;
        a[i] = *(const short8*)&sb[(ar * 8 + ((sl * 4 + hi) ^ sw)) * 8];
      }
#pragma unroll
      for (int j = 0; j < 2; ++j) {
        int br = wn * 32 + j * 16 + fm;
        b[j] = *(const short8*)&sb[4096 + (br * 8 + ((sl * 4 + hi) ^ sw)) * 8];
      }
#pragma unroll
      for (int i = 0; i < 2; ++i)
#pragma unroll
        for (int j = 0; j < 2; ++j)
          acc[i][j] = __builtin_amdgcn_mfma_f32_16x16x32_bf16(a[i], b[j], acc[i][j], 0, 0, 0);
    }
  }
  MEMFENCE;
}

// ---------------------------------------------------------------------------
// 128x64 block tile, BK=64, ring-3 (3 x 24KB). Used by k_gemm_oh_ah.
// ---------------------------------------------------------------------------
__device__ inline void gemm_core128(const short* __restrict__ A, int lda,
                                    const short* __restrict__ BT, int ldb,
                                    int Ktot, short* lds, floatx4 acc[4][2]) {
  const int tid = threadIdx.x, lane = tid & 63, w = tid >> 6;
  const int wm = w >> 1, wn = w & 1;
  const int fm = lane & 15, hi = lane >> 4;

  const int r0 = tid >> 3;
  const int g0 = (tid & 7) ^ (r0 & 7);
  const short* gA0 = A + (size_t)r0 * lda + g0 * 8;
  const short* gA1 = A + (size_t)(r0 + 32) * lda + g0 * 8;
  const short* gA2 = A + (size_t)(r0 + 64) * lda + g0 * 8;
  const short* gA3 = A + (size_t)(r0 + 96) * lda + g0 * 8;
  const short* gB0 = BT + (size_t)r0 * ldb + g0 * 8;
  const short* gB1 = BT + (size_t)(r0 + 32) * ldb + g0 * 8;
  const int dA0 = tid * 8,          dA1 = (256 + tid) * 8;
  const int dA2 = (512 + tid) * 8,  dA3 = (768 + tid) * 8;
  const int dB0 = 8192 + tid * 8,   dB1 = 8192 + (256 + tid) * 8;

  const int nIter = Ktot >> 6;

  auto stage = [&](int t) {
    short* d = lds + (t % 3) * 12288;
    int ko = t * 64;
    async_copy16(gA0 + ko, d + dA0);
    async_copy16(gA1 + ko, d + dA1);
    async_copy16(gA2 + ko, d + dA2);
    async_copy16(gA3 + ko, d + dA3);
    async_copy16(gB0 + ko, d + dB0);
    async_copy16(gB1 + ko, d + dB1);
  };

  const int sw = fm & 7;

  stage(0);
  stage(1);
  for (int it = 0; it < nIter; ++it) {
    if (it + 1 < nIter) __builtin_amdgcn_s_waitcnt(VMCNT(6));
    else                __builtin_amdgcn_s_waitcnt(VMCNT(0));
    MEMFENCE;
    __builtin_amdgcn_s_barrier();
    MEMFENCE;
    if (it + 2 < nIter) stage(it + 2);
    const short* sb = lds + (it % 3) * 12288;
#pragma unroll
    for (int sl = 0; sl < 2; ++sl) {
      short8 a[4], b[2];
#pragma unroll
      for (int i = 0; i < 4; ++i) {
        int ar = wm * 64 + i * 16 + fm;
        a[i] = *(const short8*)&sb[(ar * 8 + ((sl * 4 + hi) ^ sw)) * 8];
      }
#pragma unroll
      for (int j = 0; j < 2; ++j) {
        int br = wn * 32 + j * 16 + fm;
        b[j] = *(const short8*)&sb[8192 + (br * 8 + ((sl * 4 + hi) ^ sw)) * 8];
      }
#pragma unroll
      for (int i = 0; i < 4; ++i)
#pragma unroll
        for (int j = 0; j < 2; ++j)
          acc[i][j] = __builtin_amdgcn_mfma_f32_16x16x32_bf16(a[i], b[j], acc[i][j], 0, 0, 0);
    }
  }
  MEMFENCE;
}

// ---------------------------------------------------------------------------
// 256x128 block tile, BK=32, ring-3 (3 x 24KB = 72KB -> 2 blocks/CU),
// 512 threads = 8 waves in 4m x 2n, wave-tile 64x64. Swizzle (row>>1)&3
// (verified conflict-free in R3). Used for the hoisted GEMM (k_pah).
// ---------------------------------------------------------------------------
__device__ inline void gemm_core256x128(const short* __restrict__ A, int lda,
                                        const short* __restrict__ BT, int ldb,
                                        int Ktot, short* lds, floatx4 acc[4][4]) {
  const int tid = threadIdx.x, lane = tid & 63, w = tid >> 6;
  const int wm = w >> 1, wn = w & 1;          // 4 x 2 wave grid
  const int fm = lane & 15, hi = lane >> 4;

  const int r0 = tid >> 2;                    // row 0..127
  const int c0 = tid & 3;
  const int g0 = c0 ^ ((r0 >> 1) & 3);        // (r0+128)>>1 & 3 == (r0>>1)&3
  const short* gA0 = A + (size_t)r0 * lda + g0 * 8;
  const short* gA1 = A + (size_t)(r0 + 128) * lda + g0 * 8;
  const short* gB0 = BT + (size_t)r0 * ldb + g0 * 8;
  const int dA0 = tid * 8, dA1 = (512 + tid) * 8;
  const int dB0 = 8192 + tid * 8;             // B base = 8192 shorts (16KB)

  const int nIter = Ktot >> 5;

  auto stage = [&](int t) {
    short* d = lds + (t % 3) * 12288;         // slot = 24KB = 12288 shorts
    int ko = t * 32;
    async_copy16(gA0 + ko, d + dA0);
    async_copy16(gA1 + ko, d + dA1);
    async_copy16(gB0 + ko, d + dB0);
  };

  const int swz = (fm >> 1) & 3;              // (row>>1)&3 for row = 16k + fm

  stage(0);
  stage(1);
  for (int it = 0; it < nIter; ++it) {
    if (it + 1 < nIter) __builtin_amdgcn_s_waitcnt(VMCNT(3));
    else                __builtin_amdgcn_s_waitcnt(VMCNT(0));
    MEMFENCE;
    __builtin_amdgcn_s_barrier();
    MEMFENCE;
    if (it + 2 < nIter) stage(it + 2);
    const short* sb = lds + (it % 3) * 12288;
    short8 a[4], b[4];
#pragma unroll
    for (int i = 0; i < 4; ++i) {
      int ar = wm * 64 + i * 16 + fm;         // 0..255
      a[i] = *(const short8*)&sb[(ar * 4 + (hi ^ swz)) * 8];
    }
#pragma unroll
    for (int j = 0; j < 4; ++j) {
      int br = wn * 64 + j * 16 + fm;         // 0..127
      b[j] = *(const short8*)&sb[8192 + (br * 4 + (hi ^ swz)) * 8];
    }
#pragma unroll
    for (int i = 0; i < 4; ++i)
#pragma unroll
      for (int j = 0; j < 4; ++j)
        acc[i][j] = __builtin_amdgcn_mfma_f32_16x16x32_bf16(a[i], b[j], acc[i][j], 0, 0, 0);
  }
  MEMFENCE;
}

// ---------------- setup kernels ----------------

// [R6-keep] all weight/input preps fused into one dispatch.
// blocks [0,10240): WbT  [1024 n][2560 k] = [w_hp ; w_pp(0 diag) ; w_cp]^T
// blocks [10240,12288): WpcT [512 n][1024 k]
// blocks [12288,14336): WohT [1024 n][512 k]
// blocks [14336,18432): inb (bf16 cast of inputs)
__global__ void k_build_all(const float* __restrict__ w_hp, const float* __restrict__ w_pp,
                            const float* __restrict__ w_cp, const float* __restrict__ w_pc,
                            const float* __restrict__ w_oh, const float* __restrict__ inp,
                            short* __restrict__ WbT, short* __restrict__ WpcT,
                            short* __restrict__ WohT, short* __restrict__ inb) {
  int bx = blockIdx.x, tid = threadIdx.x;
  if (bx < 10240) {
    int idx = bx * 256 + tid;                     // 1024*2560
    int n = idx / K_BIG, k = idx - n * K_BIG;
    float v;
    if (k < 1024) v = w_hp[k * P_DIM + n];
    else if (k < 2048) { int r = k - 1024; v = (r == n) ? 0.f : w_pp[r * P_DIM + n]; }
    else v = w_cp[(k - 2048) * P_DIM + n];
    WbT[idx] = f2bf(v);
  } else if (bx < 12288) {
    int idx = (bx - 10240) * 256 + tid;           // 512*1024
    int n = idx >> 10, k = idx & 1023;
    WpcT[idx] = f2bf(w_pc[k * C_DIM + n]);
  } else if (bx < 14336) {
    int idx = (bx - 12288) * 256 + tid;           // 1024*512
    int n = idx >> 9, k = idx & 511;
    WohT[idx] = f2bf(w_oh[k * H_DIM + n]);
  } else {
    int idx = (bx - 14336) * 256 + tid;           // 2048*512
    inb[idx] = f2bf(inp[idx]);
  }
}

// [R7] oh GEMM with fused Ah epilogue: computes oh = inputs@w_oh + bias_h in
// registers, then writes Ah[t'] = bf16(sigmoid((1-0.75^t')*oh)) for t'=1..11
// directly. No oh array, no separate k_ah pass (saves its 88MB oh re-reads
// + one dispatch). ct sequence is the same successive-multiply as before.
__global__ __launch_bounds__(256, 2) void k_gemm_oh_ah(const short* __restrict__ inb,
                                                       const short* __restrict__ WohT,
                                                       const float* __restrict__ bias_h,
                                                       short* __restrict__ Ah) {
  __shared__ short lds[36864];
  floatx4 acc[4][2] = {};
  int m0 = (blockIdx.x & 15) * 128, n0 = (blockIdx.x >> 4) * 64;
  gemm_core128(inb + (size_t)m0 * O_DIM, O_DIM, WohT + (size_t)n0 * O_DIM, O_DIM,
               O_DIM, lds, acc);
  const int lane = threadIdx.x & 63;
  const int fm = lane & 15, hi = lane >> 4;
  const int w = threadIdx.x >> 6, wm = w >> 1, wn = w & 1;
  // add bias in place (f32 value identical to the old materialized oh)
#pragma unroll
  for (int i = 0; i < 4; ++i)
#pragma unroll
    for (int j = 0; j < 2; ++j)
#pragma unroll
      for (int r = 0; r < 4; ++r) {
        int n = n0 + wn * 32 + j * 16 + fm;
        acc[i][j][r] += bias_h[n];
      }
  float o = 1.0f;
  for (int tp = 1; tp <= 11; ++tp) {
    o *= OMT;                                 // o = 0.75^tp (successive mult)
    float ct = 1.0f - o;
    short* dst = Ah + (size_t)(tp - 1) * B_DIM * H_DIM;
#pragma unroll
    for (int i = 0; i < 4; ++i)
#pragma unroll
      for (int j = 0; j < 2; ++j)
#pragma unroll
        for (int r = 0; r < 4; ++r) {
          int m = m0 + wm * 64 + i * 16 + hi * 4 + r;
          int n = n0 + wn * 32 + j * 16 + fm;
          dst[(size_t)m * H_DIM + n] = f2bf(sigmoidf_(ct * acc[i][j][r]));
        }
  }
}

// P_ah = Ah[11*2048 x 1024] @ w_hp  (K=1024), raw f32 -> Pdst (= out + 2048*1024)
// grid 704 = 88 m-panels (256 rows) x 8 n-panels (128 cols), 512 threads.
// XCD-chunked bijective remap (704 = 8*88).
__global__ __launch_bounds__(512, 4) void k_pah(const short* __restrict__ Ah,
                                                const short* __restrict__ WbT,
                                                float* __restrict__ Pdst) {
  __shared__ short lds[36864];            // 72KB: 3-ring x (16KB A + 8KB B)
  floatx4 acc[4][4] = {};
  int logical = (blockIdx.x & 7) * 88 + (blockIdx.x >> 3);
  int m = logical >> 3, n = logical & 7;
  int m0 = m * 256, n0 = n * 128;
  gemm_core256x128(Ah + (size_t)m0 * H_DIM, H_DIM, WbT + (size_t)n0 * K_BIG, K_BIG,
                   H_DIM, lds, acc);
  const int lane = threadIdx.x & 63;
  const int fm = lane & 15, hi = lane >> 4;
  const int w = threadIdx.x >> 6, wm = w >> 1, wn = w & 1;
#pragma unroll
  for (int i = 0; i < 4; ++i)
#pragma unroll
    for (int j = 0; j < 4; ++j)
#pragma unroll
      for (int r = 0; r < 4; ++r) {
        int rr = m0 + wm * 64 + i * 16 + hi * 4 + r;
        int nn = n0 + wn * 64 + j * 16 + fm;
        Pdst[(size_t)rr * P_DIM + nn] = acc[i][j][r];
      }
}

// Step 1 is rank-1 (all states = 0.5): column sums of WbT / WpcT.
// 384 blocks x 4 waves; wave r sums one row.
__global__ void k_step1a(const short* __restrict__ WbT, const short* __restrict__ WpcT,
                         const float* __restrict__ bias_p, const float* __restrict__ bias_c,
                         float* __restrict__ p1v, float* __restrict__ ap1v,
                         float* __restrict__ c1v, float* __restrict__ ac1v) {
  int r = blockIdx.x * 4 + (threadIdx.x >> 6);
  int lane = threadIdx.x & 63;
  float s = 0.f;
  if (r < 1024) {
    const short* row = WbT + (size_t)r * K_BIG;
    for (int k = lane; k < K_BIG; k += 64)
      s += __uint_as_float(((uint32_t)(uint16_t)row[k]) << 16);
  } else {
    const short* row = WpcT + (size_t)(r - 1024) * P_DIM;
    for (int k = lane; k < P_DIM; k += 64)
      s += __uint_as_float(((uint32_t)(uint16_t)row[k]) << 16);
  }
#pragma unroll
  for (int off = 32; off > 0; off >>= 1) s += __shfl_down(s, off, 64);
  if (lane == 0) {
    if (r < 1024) {
      float pv = TAU * (0.5f * s + bias_p[r]);
      p1v[r] = pv; ap1v[r] = sigmoidf_(pv);
    } else {
      int n = r - 1024;
      float cv = TAU * (0.5f * s + bias_c[n]);
      c1v[n] = cv; ac1v[n] = sigmoidf_(cv);
    }
  }
}

// Broadcast step-1 results: fill out[0], X1 (ap|ac), p, c.  grid (6, 2048)
__global__ void k_step1b(const float* __restrict__ p1v, const float* __restrict__ ap1v,
                         const float* __restrict__ c1v, const float* __restrict__ ac1v,
                         short* __restrict__ X1, float* __restrict__ p,
                         float* __restrict__ c, float* __restrict__ out0) {
  int n = blockIdx.x * 256 + threadIdx.x;         // 0..1535
  int m = blockIdx.y;
  if (n < 1024) {
    float ap = ap1v[n];
    X1[(size_t)m * K_REC + n] = f2bf(ap);
    out0[(size_t)m * P_DIM + n] = ap;
    p[(size_t)m * P_DIM + n] = p1v[n];
  } else {
    int nn = n - 1024;
    X1[(size_t)m * K_REC + n] = f2bf(ac1v[nn]);
    c[(size_t)m * C_DIM + nn] = c1v[nn];
  }
}

// ---------------- per-timestep fused kernel (t = 2..12) ----------------
// blocks [0,512): big GEMM X(2048x1536)@WbT[:,1024:]^T (24 iters) -> p/ap
//   epilogue adds pah = out_t[o] (precomputed ah-part), then overwrites with ap
// blocks [512,768): small GEMM ap(2048x1024)@WpcT^T (16 iters) -> c/ac
// 768 blocks @ 3/CU: 2 big + 1 small per CU (proven balance).
__global__ __launch_bounds__(256, 3) void k_step(const short* __restrict__ Xc,
                                                 short* __restrict__ Xn,
                                                 const short* __restrict__ WbT,
                                                 const short* __restrict__ WpcT,
                                                 const float* __restrict__ bias_p,
                                                 const float* __restrict__ bias_c,
                                                 float* __restrict__ p,
                                                 float* __restrict__ c,
                                                 float* __restrict__ out_t) {
  __shared__ short lds[24576];
  floatx4 acc[2][2] = {};
  const int lane = threadIdx.x & 63;
  const int fm = lane & 15, hi = lane >> 4;
  const int w = threadIdx.x >> 6, wm = w >> 1, wn = w & 1;
  const int bx = blockIdx.x;

  if (bx < 512) {
    int m0 = (bx & 31) * 64, n0 = (bx >> 5) * 64;
    gemm_core64(Xc + (size_t)m0 * K_REC, K_REC,
                WbT + (size_t)n0 * K_BIG + H_DIM, K_BIG,
                K_REC, lds, acc);
#pragma unroll
    for (int i = 0; i < 2; ++i)
#pragma unroll
      for (int j = 0; j < 2; ++j)
#pragma unroll
        for (int r = 0; r < 4; ++r) {
          int m = m0 + wm * 32 + i * 16 + hi * 4 + r;
          int n = n0 + wn * 32 + j * 16 + fm;
          size_t o = (size_t)m * P_DIM + n;
          float pn = TAU * (acc[i][j][r] + out_t[o] + bias_p[n]) + OMT * p[o];
          p[o] = pn;
          float ap = sigmoidf_(pn);
          out_t[o] = ap;
          Xn[(size_t)m * K_REC + n] = f2bf(ap);
        }
  } else {
    int v = bx - 512;
    int m0 = (v >> 3) * 64, n0 = (v & 7) * 64;
    gemm_core64(Xc + (size_t)m0 * K_REC, K_REC,
                WpcT + (size_t)n0 * P_DIM, P_DIM,
                P_DIM, lds, acc);
#pragma unroll
    for (int i = 0; i < 2; ++i)
#pragma unroll
      for (int j = 0; j < 2; ++j)
#pragma unroll
        for (int r = 0; r < 4; ++r) {
          int m = m0 + wm * 32 + i * 16 + hi * 4 + r;
          int n = n0 + wn * 32 + j * 16 + fm;
          size_t o = (size_t)m * C_DIM + n;
          float cn = TAU * (acc[i][j][r] + bias_c[n]) + OMT * c[o];
          c[o] = cn;
          Xn[(size_t)m * K_REC + H_DIM + n] = f2bf(sigmoidf_(cn));
        }
  }
}

extern "C" void kernel_launch(void* const* d_in, const int* in_sizes, int n_in,
                              void* d_out, int out_size, void* d_ws, size_t ws_size,
                              hipStream_t stream) {
  const float* inputs = (const float*)d_in[0];
  const float* w_oh   = (const float*)d_in[1];
  const float* w_hp   = (const float*)d_in[2];
  const float* w_pp   = (const float*)d_in[3];
  const float* w_pc   = (const float*)d_in[4];
  const float* w_cp   = (const float*)d_in[5];
  const float* bias_h = (const float*)d_in[6];
  const float* bias_p = (const float*)d_in[7];
  const float* bias_c = (const float*)d_in[8];
  float* out = (float*)d_out;

  char* ws = (char*)d_ws;
  auto alloc = [&](size_t bytes) {
    char* q = ws;
    ws += (bytes + 255) & ~(size_t)255;
    return q;
  };
  short* WbT  = (short*)alloc((size_t)P_DIM * K_BIG * 2);          // 5.2 MB
  short* WpcT = (short*)alloc((size_t)C_DIM * P_DIM * 2);          // 1 MB
  short* WohT = (short*)alloc((size_t)H_DIM * O_DIM * 2);          // 1 MB
  short* inb  = (short*)alloc((size_t)B_DIM * O_DIM * 2);          // 2 MB
  short* Ah   = (short*)alloc((size_t)11 * B_DIM * H_DIM * 2);     // 46 MB
  short* XA   = (short*)alloc((size_t)B_DIM * K_REC * 2);          // 6.3 MB
  short* XB   = (short*)alloc((size_t)B_DIM * K_REC * 2);          // 6.3 MB
  float* p    = (float*)alloc((size_t)B_DIM * P_DIM * 4);          // 8 MB
  float* c    = (float*)alloc((size_t)B_DIM * C_DIM * 4);          // 4 MB
  float* p1v  = (float*)alloc(1024 * 4);
  float* ap1v = (float*)alloc(1024 * 4);
  float* c1v  = (float*)alloc(512 * 4);
  float* ac1v = (float*)alloc(512 * 4);

  // fused weight/input prep
  k_build_all<<<dim3(18432), 256, 0, stream>>>(w_hp, w_pp, w_cp, w_pc, w_oh, inputs,
                                               WbT, WpcT, WohT, inb);

  // oh GEMM + fused Ah generation (t'=1..11)
  k_gemm_oh_ah<<<dim3(256), 256, 0, stream>>>(inb, WohT, bias_h, Ah);

  // hoisted ah-part of the p pre-activation, stored into out slots 1..11
  k_pah<<<dim3(704), 512, 0, stream>>>(Ah, WbT, out + (size_t)B_DIM * P_DIM);

  // step 1 closed form (all states 0.5 -> rank-1)
  k_step1a<<<dim3(384), 256, 0, stream>>>(WbT, WpcT, bias_p, bias_c, p1v, ap1v, c1v, ac1v);
  k_step1b<<<dim3(6, 2048), 256, 0, stream>>>(p1v, ap1v, c1v, ac1v, XA, p, c, out);

  // recurrent steps t = 2..12 (X for step-t output lives in Xs[t&1])
  short* Xs[2] = {XB, XA};      // Xs[1] = XA holds X1
  for (int t = 2; t <= 12; ++t) {
    k_step<<<dim3(768), 256, 0, stream>>>(Xs[(t - 1) & 1], Xs[t & 1],
                                          WbT, WpcT, bias_p, bias_c, p, c,
                                          out + (size_t)(t - 1) * B_DIM * P_DIM);
  }
}

// Round 8
// 448.423 us; speedup vs baseline: 7.1708x; 1.0326x over previous
//
#include <hip/hip_runtime.h>
#include <stdint.h>
#include <math.h>

typedef __attribute__((ext_vector_type(8))) short short8;
typedef __attribute__((ext_vector_type(4))) float floatx4;

#define B_DIM 2048
#define O_DIM 512
#define H_DIM 1024
#define P_DIM 1024
#define C_DIM 512
#define K_BIG 2560   // H + P + C (WbT row length)
#define K_REC 1536   // P + C    (recurrent X width)
#define TAU 0.25f
#define OMT 0.75f

// s_waitcnt imm (gfx9): vmcnt [3:0]+[15:14], exp [6:4]=7, lgkm [11:8]=15 (no wait)
#define VMCNT(n) (((n) & 15) | (((n) >> 4) << 14) | 0x0F70)
#define MEMFENCE asm volatile("" ::: "memory")

__device__ inline short f2bf(float f) {
  uint32_t u = __float_as_uint(f);
  u += 0x7FFFu + ((u >> 16) & 1u);   // round-to-nearest-even
  return (short)(u >> 16);
}

__device__ inline float bf2f(short s) {
  return __uint_as_float(((uint32_t)(uint16_t)s) << 16);
}

__device__ inline float bfround(float f) { return bf2f(f2bf(f)); }

__device__ inline float sigmoidf_(float x) {
  return 1.0f / (1.0f + __expf(-x));
}

__device__ inline void async_copy16(const void* g, void* l) {
  __builtin_amdgcn_global_load_lds((__attribute__((address_space(1))) void*)g,
                                   (__attribute__((address_space(3))) void*)l,
                                   16, 0, 0);
}

// ---------------------------------------------------------------------------
// 64x64 block tile, BK=64, ring-3 LDS (3 x 16KB), prefetch distance 2,
// ONE barrier per K-iter. 4 waves in 2x2, wave = 32x32 via 2x2 frags.
// ---------------------------------------------------------------------------
__device__ inline void gemm_core64(const short* __restrict__ A, int lda,
                                   const short* __restrict__ BT, int ldb,
                                   int Ktot, short* lds, floatx4 acc[2][2]) {
  const int tid = threadIdx.x, lane = tid & 63, w = tid >> 6;
  const int wm = w >> 1, wn = w & 1;
  const int fm = lane & 15, hi = lane >> 4;

  const int r0 = tid >> 3;                       // row 0..31
  const int g0 = (tid & 7) ^ (r0 & 7);           // swizzled global chunk
  const short* gA0 = A + (size_t)r0 * lda + g0 * 8;
  const short* gA1 = A + (size_t)(r0 + 32) * lda + g0 * 8;   // (r0+32)&7 == r0&7
  const short* gB0 = BT + (size_t)r0 * ldb + g0 * 8;
  const short* gB1 = BT + (size_t)(r0 + 32) * ldb + g0 * 8;
  const int dA0 = tid * 8, dA1 = (256 + tid) * 8;
  const int dB0 = 4096 + tid * 8, dB1 = 4096 + (256 + tid) * 8;

  const int nIter = Ktot >> 6;

  auto stage = [&](int t) {
    short* d = lds + (t % 3) * 8192;
    int ko = t * 64;
    async_copy16(gA0 + ko, d + dA0);
    async_copy16(gA1 + ko, d + dA1);
    async_copy16(gB0 + ko, d + dB0);
    async_copy16(gB1 + ko, d + dB1);
  };

  const int sw = fm & 7;

  stage(0);
  stage(1);
  for (int it = 0; it < nIter; ++it) {
    if (it + 1 < nIter) __builtin_amdgcn_s_waitcnt(VMCNT(4));
    else                __builtin_amdgcn_s_waitcnt(VMCNT(0));
    MEMFENCE;
    __builtin_amdgcn_s_barrier();
    MEMFENCE;
    if (it + 2 < nIter) stage(it + 2);
    const short* sb = lds + (it % 3) * 8192;
#pragma unroll
    for (int sl = 0; sl < 2; ++sl) {
      short8 a[2], b[2];
#pragma unroll
      for (int i = 0; i < 2; ++i) {
        int ar = wm * 32 + i * 16 + fm;
        a[i] = *(const short8*)&sb[(ar * 8 + ((sl * 4 + hi) ^ sw)) * 8];
      }
#pragma unroll
      for (int j = 0; j < 2; ++j) {
        int br = wn * 32 + j * 16 + fm;
        b[j] = *(const short8*)&sb[4096 + (br * 8 + ((sl * 4 + hi) ^ sw)) * 8];
      }
#pragma unroll
      for (int i = 0; i < 2; ++i)
#pragma unroll
        for (int j = 0; j < 2; ++j)
          acc[i][j] = __builtin_amdgcn_mfma_f32_16x16x32_bf16(a[i], b[j], acc[i][j], 0, 0, 0);
    }
  }
  MEMFENCE;
}

// ---------------------------------------------------------------------------
// 128x64 block tile, BK=64, ring-3 (3 x 24KB). Used by k_gemm_oh_ah.
// ---------------------------------------------------------------------------
__device__ inline void gemm_core128(const short* __restrict__ A, int lda,
                                    const short* __restrict__ BT, int ldb,
                                    int Ktot, short* lds, floatx4 acc[4][2]) {
  const int tid = threadIdx.x, lane = tid & 63, w = tid >> 6;
  const int wm = w >> 1, wn = w & 1;
  const int fm = lane & 15, hi = lane >> 4;

  const int r0 = tid >> 3;
  const int g0 = (tid & 7) ^ (r0 & 7);
  const short* gA0 = A + (size_t)r0 * lda + g0 * 8;
  const short* gA1 = A + (size_t)(r0 + 32) * lda + g0 * 8;
  const short* gA2 = A + (size_t)(r0 + 64) * lda + g0 * 8;
  const short* gA3 = A + (size_t)(r0 + 96) * lda + g0 * 8;
  const short* gB0 = BT + (size_t)r0 * ldb + g0 * 8;
  const short* gB1 = BT + (size_t)(r0 + 32) * ldb + g0 * 8;
  const int dA0 = tid * 8,          dA1 = (256 + tid) * 8;
  const int dA2 = (512 + tid) * 8,  dA3 = (768 + tid) * 8;
  const int dB0 = 8192 + tid * 8,   dB1 = 8192 + (256 + tid) * 8;

  const int nIter = Ktot >> 6;

  auto stage = [&](int t) {
    short* d = lds + (t % 3) * 12288;
    int ko = t * 64;
    async_copy16(gA0 + ko, d + dA0);
    async_copy16(gA1 + ko, d + dA1);
    async_copy16(gA2 + ko, d + dA2);
    async_copy16(gA3 + ko, d + dA3);
    async_copy16(gB0 + ko, d + dB0);
    async_copy16(gB1 + ko, d + dB1);
  };

  const int sw = fm & 7;

  stage(0);
  stage(1);
  for (int it = 0; it < nIter; ++it) {
    if (it + 1 < nIter) __builtin_amdgcn_s_waitcnt(VMCNT(6));
    else                __builtin_amdgcn_s_waitcnt(VMCNT(0));
    MEMFENCE;
    __builtin_amdgcn_s_barrier();
    MEMFENCE;
    if (it + 2 < nIter) stage(it + 2);
    const short* sb = lds + (it % 3) * 12288;
#pragma unroll
    for (int sl = 0; sl < 2; ++sl) {
      short8 a[4], b[2];
#pragma unroll
      for (int i = 0; i < 4; ++i) {
        int ar = wm * 64 + i * 16 + fm;
        a[i] = *(const short8*)&sb[(ar * 8 + ((sl * 4 + hi) ^ sw)) * 8];
      }
#pragma unroll
      for (int j = 0; j < 2; ++j) {
        int br = wn * 32 + j * 16 + fm;
        b[j] = *(const short8*)&sb[8192 + (br * 8 + ((sl * 4 + hi) ^ sw)) * 8];
      }
#pragma unroll
      for (int i = 0; i < 4; ++i)
#pragma unroll
        for (int j = 0; j < 2; ++j)
          acc[i][j] = __builtin_amdgcn_mfma_f32_16x16x32_bf16(a[i], b[j], acc[i][j], 0, 0, 0);
    }
  }
  MEMFENCE;
}

// ---------------------------------------------------------------------------
// 256x128 block tile, BK=32, ring-3 (3 x 24KB = 72KB -> 2 blocks/CU),
// 512 threads = 8 waves in 4m x 2n, wave-tile 64x64. Swizzle (row>>1)&3
// (verified conflict-free in R3). Used for the hoisted GEMM (k_pah).
// ---------------------------------------------------------------------------
__device__ inline void gemm_core256x128(const short* __restrict__ A, int lda,
                                        const short* __restrict__ BT, int ldb,
                                        int Ktot, short* lds, floatx4 acc[4][4]) {
  const int tid = threadIdx.x, lane = tid & 63, w = tid >> 6;
  const int wm = w >> 1, wn = w & 1;          // 4 x 2 wave grid
  const int fm = lane & 15, hi = lane >> 4;

  const int r0 = tid >> 2;                    // row 0..127
  const int c0 = tid & 3;
  const int g0 = c0 ^ ((r0 >> 1) & 3);        // (r0+128)>>1 & 3 == (r0>>1)&3
  const short* gA0 = A + (size_t)r0 * lda + g0 * 8;
  const short* gA1 = A + (size_t)(r0 + 128) * lda + g0 * 8;
  const short* gB0 = BT + (size_t)r0 * ldb + g0 * 8;
  const int dA0 = tid * 8, dA1 = (512 + tid) * 8;
  const int dB0 = 8192 + tid * 8;             // B base = 8192 shorts (16KB)

  const int nIter = Ktot >> 5;

  auto stage = [&](int t) {
    short* d = lds + (t % 3) * 12288;         // slot = 24KB = 12288 shorts
    int ko = t * 32;
    async_copy16(gA0 + ko, d + dA0);
    async_copy16(gA1 + ko, d + dA1);
    async_copy16(gB0 + ko, d + dB0);
  };

  const int swz = (fm >> 1) & 3;              // (row>>1)&3 for row = 16k + fm

  stage(0);
  stage(1);
  for (int it = 0; it < nIter; ++it) {
    if (it + 1 < nIter) __builtin_amdgcn_s_waitcnt(VMCNT(3));
    else                __builtin_amdgcn_s_waitcnt(VMCNT(0));
    MEMFENCE;
    __builtin_amdgcn_s_barrier();
    MEMFENCE;
    if (it + 2 < nIter) stage(it + 2);
    const short* sb = lds + (it % 3) * 12288;
    short8 a[4], b[4];
#pragma unroll
    for (int i = 0; i < 4; ++i) {
      int ar = wm * 64 + i * 16 + fm;         // 0..255
      a[i] = *(const short8*)&sb[(ar * 4 + (hi ^ swz)) * 8];
    }
#pragma unroll
    for (int j = 0; j < 4; ++j) {
      int br = wn * 64 + j * 16 + fm;         // 0..127
      b[j] = *(const short8*)&sb[8192 + (br * 4 + (hi ^ swz)) * 8];
    }
#pragma unroll
    for (int i = 0; i < 4; ++i)
#pragma unroll
      for (int j = 0; j < 4; ++j)
        acc[i][j] = __builtin_amdgcn_mfma_f32_16x16x32_bf16(a[i], b[j], acc[i][j], 0, 0, 0);
  }
  MEMFENCE;
}

// ---------------- setup kernels ----------------

// all weight/input preps fused into one dispatch.
__global__ void k_build_all(const float* __restrict__ w_hp, const float* __restrict__ w_pp,
                            const float* __restrict__ w_cp, const float* __restrict__ w_pc,
                            const float* __restrict__ w_oh, const float* __restrict__ inp,
                            short* __restrict__ WbT, short* __restrict__ WpcT,
                            short* __restrict__ WohT, short* __restrict__ inb) {
  int bx = blockIdx.x, tid = threadIdx.x;
  if (bx < 10240) {
    int idx = bx * 256 + tid;                     // 1024*2560
    int n = idx / K_BIG, k = idx - n * K_BIG;
    float v;
    if (k < 1024) v = w_hp[k * P_DIM + n];
    else if (k < 2048) { int r = k - 1024; v = (r == n) ? 0.f : w_pp[r * P_DIM + n]; }
    else v = w_cp[(k - 2048) * P_DIM + n];
    WbT[idx] = f2bf(v);
  } else if (bx < 12288) {
    int idx = (bx - 10240) * 256 + tid;           // 512*1024
    int n = idx >> 10, k = idx & 1023;
    WpcT[idx] = f2bf(w_pc[k * C_DIM + n]);
  } else if (bx < 14336) {
    int idx = (bx - 12288) * 256 + tid;           // 1024*512
    int n = idx >> 9, k = idx & 511;
    WohT[idx] = f2bf(w_oh[k * H_DIM + n]);
  } else {
    int idx = (bx - 14336) * 256 + tid;           // 2048*512
    inb[idx] = f2bf(inp[idx]);
  }
}

// oh GEMM with fused Ah epilogue (t'=1..11).
__global__ __launch_bounds__(256, 2) void k_gemm_oh_ah(const short* __restrict__ inb,
                                                       const short* __restrict__ WohT,
                                                       const float* __restrict__ bias_h,
                                                       short* __restrict__ Ah) {
  __shared__ short lds[36864];
  floatx4 acc[4][2] = {};
  int m0 = (blockIdx.x & 15) * 128, n0 = (blockIdx.x >> 4) * 64;
  gemm_core128(inb + (size_t)m0 * O_DIM, O_DIM, WohT + (size_t)n0 * O_DIM, O_DIM,
               O_DIM, lds, acc);
  const int lane = threadIdx.x & 63;
  const int fm = lane & 15, hi = lane >> 4;
  const int w = threadIdx.x >> 6, wm = w >> 1, wn = w & 1;
#pragma unroll
  for (int i = 0; i < 4; ++i)
#pragma unroll
    for (int j = 0; j < 2; ++j)
#pragma unroll
      for (int r = 0; r < 4; ++r) {
        int n = n0 + wn * 32 + j * 16 + fm;
        acc[i][j][r] += bias_h[n];
      }
  float o = 1.0f;
  for (int tp = 1; tp <= 11; ++tp) {
    o *= OMT;                                 // o = 0.75^tp
    float ct = 1.0f - o;
    short* dst = Ah + (size_t)(tp - 1) * B_DIM * H_DIM;
#pragma unroll
    for (int i = 0; i < 4; ++i)
#pragma unroll
      for (int j = 0; j < 2; ++j)
#pragma unroll
        for (int r = 0; r < 4; ++r) {
          int m = m0 + wm * 64 + i * 16 + hi * 4 + r;
          int n = n0 + wn * 32 + j * 16 + fm;
          dst[(size_t)m * H_DIM + n] = f2bf(sigmoidf_(ct * acc[i][j][r]));
        }
  }
}

// P_ah = Ah[11*2048 x 1024] @ w_hp, raw f32 -> out slots 1..11.
__global__ __launch_bounds__(512, 4) void k_pah(const short* __restrict__ Ah,
                                                const short* __restrict__ WbT,
                                                float* __restrict__ Pdst) {
  __shared__ short lds[36864];            // 72KB: 3-ring x (16KB A + 8KB B)
  floatx4 acc[4][4] = {};
  int logical = (blockIdx.x & 7) * 88 + (blockIdx.x >> 3);
  int m = logical >> 3, n = logical & 7;
  int m0 = m * 256, n0 = n * 128;
  gemm_core256x128(Ah + (size_t)m0 * H_DIM, H_DIM, WbT + (size_t)n0 * K_BIG, K_BIG,
                   H_DIM, lds, acc);
  const int lane = threadIdx.x & 63;
  const int fm = lane & 15, hi = lane >> 4;
  const int w = threadIdx.x >> 6, wm = w >> 1, wn = w & 1;
#pragma unroll
  for (int i = 0; i < 4; ++i)
#pragma unroll
    for (int j = 0; j < 4; ++j)
#pragma unroll
      for (int r = 0; r < 4; ++r) {
        int rr = m0 + wm * 64 + i * 16 + hi * 4 + r;
        int nn = n0 + wn * 64 + j * 16 + fm;
        Pdst[(size_t)rr * P_DIM + nn] = acc[i][j][r];
      }
}

// Step 1 is rank-1 (all states = 0.5): column sums of WbT / WpcT.
__global__ void k_step1a(const short* __restrict__ WbT, const short* __restrict__ WpcT,
                         const float* __restrict__ bias_p, const float* __restrict__ bias_c,
                         float* __restrict__ p1v, float* __restrict__ ap1v,
                         float* __restrict__ c1v, float* __restrict__ ac1v) {
  int r = blockIdx.x * 4 + (threadIdx.x >> 6);
  int lane = threadIdx.x & 63;
  float s = 0.f;
  if (r < 1024) {
    const short* row = WbT + (size_t)r * K_BIG;
    for (int k = lane; k < K_BIG; k += 64) s += bf2f(row[k]);
  } else {
    const short* row = WpcT + (size_t)(r - 1024) * P_DIM;
    for (int k = lane; k < P_DIM; k += 64) s += bf2f(row[k]);
  }
#pragma unroll
  for (int off = 32; off > 0; off >>= 1) s += __shfl_down(s, off, 64);
  if (lane == 0) {
    if (r < 1024) {
      float pv = TAU * (0.5f * s + bias_p[r]);
      p1v[r] = pv; ap1v[r] = sigmoidf_(pv);
    } else {
      int n = r - 1024;
      float cv = TAU * (0.5f * s + bias_c[n]);
      c1v[n] = cv; ac1v[n] = sigmoidf_(cv);
    }
  }
}

// [R8] Step 2 is also rank-1 on the recurrent side: X1 rows are identical
// across batch, so the step-2 GEMMs collapse to a mat-vec. Wave r computes
// row r's dot with the bf16-quantized x1 vector (exactly the values the
// GEMM would have read from X1).
// r<1024:  Q[r]  = TAU*(x1 . WbT[r][1024:] + bias_p[r]) + OMT*p1v[r]
// r>=1024: C2[n] = TAU*(ap1 . WpcT[n][:]  + bias_c[n]) + OMT*c1v[n]
__global__ void k_qvec(const short* __restrict__ WbT, const short* __restrict__ WpcT,
                       const float* __restrict__ bias_p, const float* __restrict__ bias_c,
                       const float* __restrict__ p1v, const float* __restrict__ ap1v,
                       const float* __restrict__ c1v, const float* __restrict__ ac1v,
                       float* __restrict__ Q, float* __restrict__ C2,
                       short* __restrict__ ac2b) {
  int r = blockIdx.x * 4 + (threadIdx.x >> 6);
  int lane = threadIdx.x & 63;
  float s = 0.f;
  if (r < 1024) {
    const short* row = WbT + (size_t)r * K_BIG + H_DIM;
    for (int k = lane; k < K_REC; k += 64) {
      float xv = (k < P_DIM) ? bfround(ap1v[k]) : bfround(ac1v[k - P_DIM]);
      s += xv * bf2f(row[k]);
    }
  } else {
    int nn = r - 1024;
    const short* row = WpcT + (size_t)nn * P_DIM;
    for (int k = lane; k < P_DIM; k += 64)
      s += bfround(ap1v[k]) * bf2f(row[k]);
  }
#pragma unroll
  for (int off = 32; off > 0; off >>= 1) s += __shfl_down(s, off, 64);
  if (lane == 0) {
    if (r < 1024) {
      Q[r] = TAU * (s + bias_p[r]) + OMT * p1v[r];
    } else {
      int nn = r - 1024;
      float cv = TAU * (s + bias_c[nn]) + OMT * c1v[nn];
      C2[nn] = cv;
      ac2b[nn] = f2bf(sigmoidf_(cv));
    }
  }
}

// out[0] broadcast (X1/p/c fills are dead now: step 2 consumes p1v/c1v via
// Q/C2 and writes p2/c2 itself; XA is first written at t=3).
__global__ void k_out0(const float* __restrict__ ap1v, float* __restrict__ out0) {
  int n = blockIdx.x * 256 + threadIdx.x;         // 0..1023
  out0[(size_t)blockIdx.y * P_DIM + n] = ap1v[n];
}

// [R8] step 2 as elementwise: pn = TAU*pah + Q[n] (Q holds TAU*(x1.W+bias)
// + OMT*p1). Writes p, out[1] (ap2), X2; c/ac2 are column-constant.
__global__ void k_step2(const float* __restrict__ Q, const float* __restrict__ C2,
                        const short* __restrict__ ac2b, float* __restrict__ p,
                        float* __restrict__ c, float* __restrict__ out1,
                        short* __restrict__ X2) {
  int n = blockIdx.x * 256 + threadIdx.x;         // 0..1535
  int m = blockIdx.y;
  if (n < P_DIM) {
    size_t o = (size_t)m * P_DIM + n;
    float pn = TAU * out1[o] + Q[n];
    p[o] = pn;
    float ap = sigmoidf_(pn);
    out1[o] = ap;
    X2[(size_t)m * K_REC + n] = f2bf(ap);
  } else {
    int nn = n - P_DIM;
    X2[(size_t)m * K_REC + n] = ac2b[nn];
    c[(size_t)m * C_DIM + nn] = C2[nn];
  }
}

// ---------------- per-timestep fused kernel (t = 3..12) ----------------
// blocks [0,512): big GEMM X(2048x1536)@WbT[:,1024:]^T -> p/ap update.
//   mapping m-tile = bx&31, n-tile = bx>>5: XCD x owns m = x mod 8 (4 slabs,
//   768KB L2-resident) — already partitioned.
// blocks [512,768): small GEMM ap(2048x1024)@WpcT^T -> c/ac.
//   [R8] remap m-tile = (v&7) + 8*(idx&3): aligns the small GEMM's A-slabs
//   with the big GEMM's per-XCD slab set (was: all 32 slabs = 4MB/XCD ->
//   L2 thrash; now shared 512KB). n-tile = idx>>2.
__global__ __launch_bounds__(256, 3) void k_step(const short* __restrict__ Xc,
                                                 short* __restrict__ Xn,
                                                 const short* __restrict__ WbT,
                                                 const short* __restrict__ WpcT,
                                                 const float* __restrict__ bias_p,
                                                 const float* __restrict__ bias_c,
                                                 float* __restrict__ p,
                                                 float* __restrict__ c,
                                                 float* __restrict__ out_t) {
  __shared__ short lds[24576];
  floatx4 acc[2][2] = {};
  const int lane = threadIdx.x & 63;
  const int fm = lane & 15, hi = lane >> 4;
  const int w = threadIdx.x >> 6, wm = w >> 1, wn = w & 1;
  const int bx = blockIdx.x;

  if (bx < 512) {
    int m0 = (bx & 31) * 64, n0 = (bx >> 5) * 64;
    gemm_core64(Xc + (size_t)m0 * K_REC, K_REC,
                WbT + (size_t)n0 * K_BIG + H_DIM, K_BIG,
                K_REC, lds, acc);
#pragma unroll
    for (int i = 0; i < 2; ++i)
#pragma unroll
      for (int j = 0; j < 2; ++j)
#pragma unroll
        for (int r = 0; r < 4; ++r) {
          int m = m0 + wm * 32 + i * 16 + hi * 4 + r;
          int n = n0 + wn * 32 + j * 16 + fm;
          size_t o = (size_t)m * P_DIM + n;
          float pn = TAU * (acc[i][j][r] + out_t[o] + bias_p[n]) + OMT * p[o];
          p[o] = pn;
          float ap = sigmoidf_(pn);
          out_t[o] = ap;
          Xn[(size_t)m * K_REC + n] = f2bf(ap);
        }
  } else {
    int v = bx - 512;
    int idx = v >> 3;
    int m0 = ((v & 7) + 8 * (idx & 3)) * 64, n0 = (idx >> 2) * 64;
    gemm_core64(Xc + (size_t)m0 * K_REC, K_REC,
                WpcT + (size_t)n0 * P_DIM, P_DIM,
                P_DIM, lds, acc);
#pragma unroll
    for (int i = 0; i < 2; ++i)
#pragma unroll
      for (int j = 0; j < 2; ++j)
#pragma unroll
        for (int r = 0; r < 4; ++r) {
          int m = m0 + wm * 32 + i * 16 + hi * 4 + r;
          int n = n0 + wn * 32 + j * 16 + fm;
          size_t o = (size_t)m * C_DIM + n;
          float cn = TAU * (acc[i][j][r] + bias_c[n]) + OMT * c[o];
          c[o] = cn;
          Xn[(size_t)m * K_REC + H_DIM + n] = f2bf(sigmoidf_(cn));
        }
  }
}

extern "C" void kernel_launch(void* const* d_in, const int* in_sizes, int n_in,
                              void* d_out, int out_size, void* d_ws, size_t ws_size,
                              hipStream_t stream) {
  const float* inputs = (const float*)d_in[0];
  const float* w_oh   = (const float*)d_in[1];
  const float* w_hp   = (const float*)d_in[2];
  const float* w_pp   = (const float*)d_in[3];
  const float* w_pc   = (const float*)d_in[4];
  const float* w_cp   = (const float*)d_in[5];
  const float* bias_h = (const float*)d_in[6];
  const float* bias_p = (const float*)d_in[7];
  const float* bias_c = (const float*)d_in[8];
  float* out = (float*)d_out;

  char* ws = (char*)d_ws;
  auto alloc = [&](size_t bytes) {
    char* q = ws;
    ws += (bytes + 255) & ~(size_t)255;
    return q;
  };
  short* WbT  = (short*)alloc((size_t)P_DIM * K_BIG * 2);          // 5.2 MB
  short* WpcT = (short*)alloc((size_t)C_DIM * P_DIM * 2);          // 1 MB
  short* WohT = (short*)alloc((size_t)H_DIM * O_DIM * 2);          // 1 MB
  short* inb  = (short*)alloc((size_t)B_DIM * O_DIM * 2);          // 2 MB
  short* Ah   = (short*)alloc((size_t)11 * B_DIM * H_DIM * 2);     // 46 MB
  short* XA   = (short*)alloc((size_t)B_DIM * K_REC * 2);          // 6.3 MB
  short* XB   = (short*)alloc((size_t)B_DIM * K_REC * 2);          // 6.3 MB
  float* p    = (float*)alloc((size_t)B_DIM * P_DIM * 4);          // 8 MB
  float* c    = (float*)alloc((size_t)B_DIM * C_DIM * 4);          // 4 MB
  float* p1v  = (float*)alloc(1024 * 4);
  float* ap1v = (float*)alloc(1024 * 4);
  float* c1v  = (float*)alloc(512 * 4);
  float* ac1v = (float*)alloc(512 * 4);
  float* Qv   = (float*)alloc(1024 * 4);
  float* C2v  = (float*)alloc(512 * 4);
  short* ac2b = (short*)alloc(512 * 2);

  // fused weight/input prep
  k_build_all<<<dim3(18432), 256, 0, stream>>>(w_hp, w_pp, w_cp, w_pc, w_oh, inputs,
                                               WbT, WpcT, WohT, inb);

  // oh GEMM + fused Ah generation (t'=1..11)
  k_gemm_oh_ah<<<dim3(256), 256, 0, stream>>>(inb, WohT, bias_h, Ah);

  // hoisted ah-part of the p pre-activation, stored into out slots 1..11
  k_pah<<<dim3(704), 512, 0, stream>>>(Ah, WbT, out + (size_t)B_DIM * P_DIM);

  // step 1 closed form (rank-1) -> step 2 closed form (rank-1 recurrent side)
  k_step1a<<<dim3(384), 256, 0, stream>>>(WbT, WpcT, bias_p, bias_c, p1v, ap1v, c1v, ac1v);
  k_qvec<<<dim3(384), 256, 0, stream>>>(WbT, WpcT, bias_p, bias_c,
                                        p1v, ap1v, c1v, ac1v, Qv, C2v, ac2b);
  k_out0<<<dim3(4, 2048), 256, 0, stream>>>(ap1v, out);
  k_step2<<<dim3(6, 2048), 256, 0, stream>>>(Qv, C2v, ac2b, p, c,
                                             out + (size_t)B_DIM * P_DIM, XB);

  // recurrent steps t = 3..12 (X for step-t output lives in Xs[t&1])
  short* Xs[2] = {XB, XA};      // Xs[0] = XB holds X2
  for (int t = 3; t <= 12; ++t) {
    k_step<<<dim3(768), 256, 0, stream>>>(Xs[(t - 1) & 1], Xs[t & 1],
                                          WbT, WpcT, bias_p, bias_c, p, c,
                                          out + (size_t)(t - 1) * B_DIM * P_DIM);
  }
}